// Round 4
// baseline (33.394 us; speedup 1.0000x reference)
//
#include <hip/hip_runtime.h>

// WImage via moment expansion (bilateral range filter -> box sums).
//
// aff(n,c) = exp(-2(n-c)^2) = e^{-2c^2} * e^{-2n^2} * e^{4nc}
//          = e^{-2c^2} * sum_k (c^k/k!) * mu_k(n),   mu_k(n) = (4n)^k e^{-2n^2}
// Window sum (21x21, zero-padded; padding n=0 -> mu_0=1, mu_k>=1 = 0):
//   tot(c) = e^{-2c^2} * ( sum_k (c^k/k!) * S_k + 441 )
// where S_k = box-sum of muh_k = mu_k - delta_k0  (muh = 0 for padding -> S_k is
// a plain zero-padded box sum). K = 14 truncation: out error <= ~4e-5.
//
//   w = tot - 1;  out = (c + 0.05*w - mn)*scale - 1
//
// 3 kernels: kH (horizontal 21-window via DPP wave prefix scans, per row),
// kC (vertical cumsum of Hhat), kV (vertical window = 2 G lookups + Horner).

#define NMOM 15
#define HH   256
#define WW   256
#define NCH  3
#define NROW (NCH * HH)          // 768 rows across channels
#define PLANE (HH * WW)          // 65536

#define K2L  (-2.8853900817779268f)   // -2*log2(e)

// ---------------- kernel H: per-row horizontal window sums ----------------
template <int CTRL, int RMASK>
__device__ __forceinline__ float dpp_add(float v) {
    int s = __builtin_amdgcn_update_dpp(0, __builtin_bit_cast(int, v),
                                        CTRL, RMASK, 0xf, true);
    return v + __builtin_bit_cast(float, s);
}

// canonical wave64 inclusive add-scan (GCN DPP sequence)
__device__ __forceinline__ float wave_iscan(float v) {
    v = dpp_add<0x111, 0xf>(v);   // row_shr:1
    v = dpp_add<0x112, 0xf>(v);   // row_shr:2
    v = dpp_add<0x114, 0xf>(v);   // row_shr:4
    v = dpp_add<0x118, 0xf>(v);   // row_shr:8
    v = dpp_add<0x142, 0xa>(v);   // row_bcast:15 -> rows 1,3
    v = dpp_add<0x143, 0xc>(v);   // row_bcast:31 -> rows 2,3
    return v;
}

__global__ __launch_bounds__(256)
void kH(const float* __restrict__ img, float* __restrict__ Hbuf) {
    __shared__ float Pl[NMOM][WW];   // full-row prefix per moment
    __shared__ float Tl[NMOM][4];    // per-wave totals

    const int x    = threadIdx.x;          // 0..255 = column
    const int wv   = x >> 6;               // wave 0..3
    const int lane = x & 63;
    const int r    = blockIdx.x;           // row id: ch*256 + y

    const float n  = img[r * WW + x];
    const float n4 = 4.0f * n;
    float mu  = __builtin_amdgcn_exp2f(K2L * n * n);  // mu_0 = e^{-2n^2}
    float val = mu - 1.0f;                            // muh_0

    float P[NMOM];
    #pragma unroll
    for (int k = 0; k < NMOM; ++k) {
        float p = wave_iscan(val);         // intra-wave inclusive prefix
        P[k] = p;
        if (lane == 63) Tl[k][wv] = p;     // wave total
        mu *= n4;                          // mu_{k+1}
        val = mu;
    }
    __syncthreads();

    #pragma unroll
    for (int k = 0; k < NMOM; ++k) {
        float off = 0.0f;                  // sum of preceding waves' totals
        if (wv > 0) off += Tl[k][0];
        if (wv > 1) off += Tl[k][1];
        if (wv > 2) off += Tl[k][2];
        Pl[k][x] = P[k] + off;             // full-row inclusive prefix
    }
    __syncthreads();

    // Hhat(x) = P(min(x+10,255)) - (x>=11 ? P(x-11) : 0)
    const int  xh  = min(x + 10, WW - 1);
    const bool hlo = (x >= 11);
    const int  xl  = hlo ? (x - 11) : 0;
    #pragma unroll
    for (int k = 0; k < NMOM; ++k) {
        float ph = Pl[k][xh];
        float pl = hlo ? Pl[k][xl] : 0.0f;
        Hbuf[(k * NROW + r) * WW + x] = ph - pl;
    }
}

// ---------------- kernel C: cumsum along y per (k, ch, x) ----------------
__global__ __launch_bounds__(256)
void kC(const float* __restrict__ Hbuf, float* __restrict__ Gbuf) {
    const int t = blockIdx.x * 256 + threadIdx.x;   // 45*256 = 11520 = 15*3*256
    const int plane = t >> 8;                       // k*3 + ch  (0..44)
    const int x     = t & 255;
    const int base  = plane * PLANE + x;

    float acc = 0.0f;
    for (int g = 0; g < 16; ++g) {
        float v[16];
        #pragma unroll
        for (int j = 0; j < 16; ++j)
            v[j] = Hbuf[base + (g * 16 + j) * WW];  // independent loads (restrict)
        #pragma unroll
        for (int j = 0; j < 16; ++j) {
            acc += v[j];
            Gbuf[base + (g * 16 + j) * WW] = acc;
        }
    }
}

// ---------------- kernel V: vertical window + Horner + epilogue ----------------
__global__ __launch_bounds__(256)
void kV(const float* __restrict__ img, const float* __restrict__ Gbuf,
        float* __restrict__ out) {
    // 1/k! table (f32)
    const float IF[NMOM] = {
        1.0f, 1.0f, 0.5f, 1.66666667e-1f, 4.16666679e-2f,
        8.33333377e-3f, 1.38888893e-3f, 1.98412701e-4f, 2.48015874e-5f,
        2.75573193e-6f, 2.75573188e-7f, 2.50521084e-8f, 2.08767563e-9f,
        1.60590438e-10f, 1.14707456e-11f };

    const int x  = threadIdx.x;
    const int r  = blockIdx.x;            // ch*256 + y
    const int ch = r >> 8;
    const int y  = r & 255;

    const float c = img[r * WW + x];

    const int  yh  = min(y + 10, HH - 1);
    const bool hlo = (y >= 11);
    const int  yl  = hlo ? (y - 11) : 0;

    float S[NMOM];
    #pragma unroll
    for (int k = 0; k < NMOM; ++k) {
        const int bk = (k * NCH + ch) * PLANE + x;
        float hi = Gbuf[bk + yh * WW];
        float lo = hlo ? Gbuf[bk + yl * WW] : 0.0f;
        S[k] = hi - lo;
    }

    // bracket = sum_k S_k c^k / k!   (Horner)
    float b = S[NMOM - 1] * IF[NMOM - 1];
    #pragma unroll
    for (int k = NMOM - 2; k >= 0; --k)
        b = fmaf(b, c, S[k] * IF[k]);

    const float e2c = __builtin_amdgcn_exp2f(K2L * c * c);
    const float tot = e2c * (b + 441.0f);   // includes self term
    const float w   = tot - 1.0f;

    const float alpha = 0.05f;
    const float mn    = -0.99261982218614470f;    // -1 + 22*exp(-8)
    const float scale = 2.0f / (23.0f - mn);      // 2/(mx-mn), mx = 23

    out[r * WW + x] = (c + alpha * w - mn) * scale - 1.0f;
}

extern "C" void kernel_launch(void* const* d_in, const int* in_sizes, int n_in,
                              void* d_out, int out_size, void* d_ws, size_t ws_size,
                              hipStream_t stream) {
    (void)in_sizes; (void)n_in; (void)out_size; (void)ws_size;
    const float* img = (const float*)d_in[0];  // d_in[1] = kernel size (21), hardcoded
    float* out  = (float*)d_out;
    float* Hbuf = (float*)d_ws;                             // 15*768*256 f32 = 11.25 MiB
    float* Gbuf = Hbuf + (size_t)NMOM * NROW * WW;          // same size, cumsum along y

    kH<<<NROW, 256, 0, stream>>>(img, Hbuf);
    kC<<<45,   256, 0, stream>>>(Hbuf, Gbuf);
    kV<<<NROW, 256, 0, stream>>>(img, Gbuf, out);
}

// Round 5
// 26.251 us; speedup vs baseline: 1.2721x; 1.2721x over previous
//
#include <hip/hip_runtime.h>

// WImage via moment expansion (bilateral range filter -> separable box sums).
//
// aff(n,c) = exp(-2(n-c)^2) = e^{-2c^2} * sum_k (c^k/k!) * mu_k(n),
//   mu_k(n) = (4n)^k e^{-2n^2};  muh_k = mu_k - delta_k0  (so zero-padding -> 0)
// tot(c) = e^{-2c^2} * ( sum_k (c^k/k!) * S_k + 441 ),  S_k = 21x21 box sum of muh_k
// w = tot - 1;  out = (c + 0.05*w - mn)*scale - 1
//
// kH: per-row horizontal 21-window of muh_k (DPP wave scans)      [768 blocks]
// kW: per (plane, 32-row seg) vertical 21-window via local cumsum [360 blocks]
// kV: 15 V-loads + Horner + epilogue                              [768 blocks]

#define NMOM 15
#define HH   256
#define WW   256
#define NCH  3
#define NROW (NCH * HH)          // 768
#define PLANE (HH * WW)          // 65536
#define NPLANES (NMOM * NCH)     // 45
#define SEGROWS 32               // vertical segment height (21 <= 32 -> halo 52 rows)

#define K2L  (-2.8853900817779268f)   // -2*log2(e)

// ---------------- kernel H: per-row horizontal window sums ----------------
template <int CTRL, int RMASK>
__device__ __forceinline__ float dpp_add(float v) {
    int s = __builtin_amdgcn_update_dpp(0, __builtin_bit_cast(int, v),
                                        CTRL, RMASK, 0xf, true);
    return v + __builtin_bit_cast(float, s);
}

// canonical wave64 inclusive add-scan
__device__ __forceinline__ float wave_iscan(float v) {
    v = dpp_add<0x111, 0xf>(v);   // row_shr:1
    v = dpp_add<0x112, 0xf>(v);   // row_shr:2
    v = dpp_add<0x114, 0xf>(v);   // row_shr:4
    v = dpp_add<0x118, 0xf>(v);   // row_shr:8
    v = dpp_add<0x142, 0xa>(v);   // row_bcast:15 -> rows 1,3
    v = dpp_add<0x143, 0xc>(v);   // row_bcast:31 -> rows 2,3
    return v;
}

__global__ __launch_bounds__(256)
void kH(const float* __restrict__ img, float* __restrict__ Hbuf) {
    __shared__ float Pl[NMOM][WW];
    __shared__ float Tl[NMOM][4];

    const int x    = threadIdx.x;
    const int wv   = x >> 6;
    const int lane = x & 63;
    const int r    = blockIdx.x;           // ch*256 + y

    const float n  = img[r * WW + x];
    const float n4 = 4.0f * n;
    float mu  = __builtin_amdgcn_exp2f(K2L * n * n);  // mu_0
    float val = mu - 1.0f;                            // muh_0

    float P[NMOM];
    #pragma unroll
    for (int k = 0; k < NMOM; ++k) {
        float p = wave_iscan(val);
        P[k] = p;
        if (lane == 63) Tl[k][wv] = p;
        mu *= n4;
        val = mu;
    }
    __syncthreads();

    #pragma unroll
    for (int k = 0; k < NMOM; ++k) {
        float off = 0.0f;
        if (wv > 0) off += Tl[k][0];
        if (wv > 1) off += Tl[k][1];
        if (wv > 2) off += Tl[k][2];
        Pl[k][x] = P[k] + off;
    }
    __syncthreads();

    const int  xh  = min(x + 10, WW - 1);
    const bool hlo = (x >= 11);
    const int  xl  = hlo ? (x - 11) : 0;
    #pragma unroll
    for (int k = 0; k < NMOM; ++k) {
        float ph = Pl[k][xh];
        float pl = hlo ? Pl[k][xl] : 0.0f;
        Hbuf[(k * NROW + r) * WW + x] = ph - pl;   // plane (k,ch), row y
    }
}

// ------- kernel W: vertical 21-window per (plane, 32-row segment) -------
// Window spans <= 2 aligned 32-row segments, so each block is independent:
// load 52 halo rows (zero outside image), local inclusive cumsum in registers,
// emit V(y) = L(i+20) - L(i-1) for its 32 output rows.
#define HALO (SEGROWS + 20)      // 52
__global__ __launch_bounds__(256)
void kW(const float* __restrict__ Hbuf, float* __restrict__ Vbuf) {
    const int x   = threadIdx.x;
    const int p   = blockIdx.x >> 3;        // plane 0..44 (k*NCH+ch ordering below)
    const int seg = blockIdx.x & 7;         // 0..7
    const int y0  = seg * SEGROWS;

    const float* __restrict__ src = Hbuf + (size_t)p * PLANE + x;
    float L[HALO];

    #pragma unroll
    for (int m = 0; m < HALO; ++m) {
        const int row = y0 - 10 + m;
        L[m] = ((unsigned)row < (unsigned)HH) ? src[row * WW] : 0.0f;
    }
    #pragma unroll
    for (int m = 1; m < HALO; ++m) L[m] += L[m - 1];

    float* __restrict__ dst = Vbuf + (size_t)p * PLANE + x;
    #pragma unroll
    for (int i = 0; i < SEGROWS; ++i) {
        const float v = (i > 0) ? (L[i + 20] - L[i - 1]) : L[20];
        dst[(y0 + i) * WW] = v;
    }
}

// ---------------- kernel V: Horner + epilogue ----------------
__global__ __launch_bounds__(256)
void kV(const float* __restrict__ img, const float* __restrict__ Vbuf,
        float* __restrict__ out) {
    const float IF[NMOM] = {
        1.0f, 1.0f, 0.5f, 1.66666667e-1f, 4.16666679e-2f,
        8.33333377e-3f, 1.38888893e-3f, 1.98412701e-4f, 2.48015874e-5f,
        2.75573193e-6f, 2.75573188e-7f, 2.50521084e-8f, 2.08767563e-9f,
        1.60590438e-10f, 1.14707456e-11f };

    const int x  = threadIdx.x;
    const int r  = blockIdx.x;            // ch*256 + y
    const int ch = r >> 8;
    const int y  = r & 255;

    const float c = img[r * WW + x];

    float S[NMOM];
    #pragma unroll
    for (int k = 0; k < NMOM; ++k)
        S[k] = Vbuf[((size_t)(k * NCH + ch)) * PLANE + y * WW + x];

    float b = S[NMOM - 1] * IF[NMOM - 1];
    #pragma unroll
    for (int k = NMOM - 2; k >= 0; --k)
        b = fmaf(b, c, S[k] * IF[k]);

    const float e2c = __builtin_amdgcn_exp2f(K2L * c * c);
    const float w   = e2c * (b + 441.0f) - 1.0f;

    const float alpha = 0.05f;
    const float mn    = -0.99261982218614470f;    // -1 + 22*exp(-8)
    const float scale = 2.0f / (23.0f - mn);      // 2/(mx-mn), mx = 23

    out[r * WW + x] = (c + alpha * w - mn) * scale - 1.0f;
}

extern "C" void kernel_launch(void* const* d_in, const int* in_sizes, int n_in,
                              void* d_out, int out_size, void* d_ws, size_t ws_size,
                              hipStream_t stream) {
    (void)in_sizes; (void)n_in; (void)out_size; (void)ws_size;
    const float* img = (const float*)d_in[0];  // d_in[1] = kernel size (21), hardcoded
    float* out  = (float*)d_out;
    float* Hbuf = (float*)d_ws;                            // 45 planes * 64KB = 11.25 MiB
    float* Vbuf = Hbuf + (size_t)NPLANES * PLANE;          // same size

    kH<<<NROW,        256, 0, stream>>>(img, Hbuf);
    kW<<<NPLANES * 8, 256, 0, stream>>>(Hbuf, Vbuf);
    kV<<<NROW,        256, 0, stream>>>(img, Vbuf, out);
}